// Round 1
// baseline (1231.269 us; speedup 1.0000x reference)
//
#include <hip/hip_runtime.h>
#include <hip/hip_bf16.h>
#include <math.h>

#define HIDDEN 768
#define NROWS 4096
#define QDIM 1024
#define VOCAB 30522
#define NPAD 30592   /* 239 * 128 */

typedef _Float16 half8 __attribute__((ext_vector_type(8)));
typedef float floatx4 __attribute__((ext_vector_type(4)));

// ---------------- proj_w (fp32 [K=1024][N=30522]) -> BT f16 [NPAD][1024] ----------------
__global__ __launch_bounds__(1024) void convert_transpose(
    const float* __restrict__ B, _Float16* __restrict__ BT) {
  __shared__ _Float16 tile[32][33];
  int n0 = blockIdx.x * 32;
  int k0 = blockIdx.y * 32;
  int tx = threadIdx.x, ty = threadIdx.y;
  int n = n0 + tx, k = k0 + ty;
  float v = (n < VOCAB) ? B[k * VOCAB + n] : 0.0f;
  tile[ty][tx] = (_Float16)v;
  __syncthreads();
  // write BT[n0+ty][k0+tx]  (coalesced in k)
  BT[(n0 + ty) * QDIM + (k0 + tx)] = tile[tx][ty];
}

// ---------------- Stage 1: h = gelu(hs @ W + b), fp32 64x64 tile ----------------
__global__ __launch_bounds__(256) void gemm1_gelu(
    const float* __restrict__ A, const float* __restrict__ W,
    const float* __restrict__ bias, float* __restrict__ H) {
  __shared__ float As[64][17];
  __shared__ float Bs[16][68];
  int t = threadIdx.x;
  int bm = blockIdx.y * 64, bn = blockIdx.x * 64;
  int tx = t & 15, ty = t >> 4;
  float acc[4][4] = {};
  for (int k0 = 0; k0 < HIDDEN; k0 += 16) {
    {
      int r = t >> 2, c = (t & 3) * 4;
      float4 v = *(const float4*)&A[(bm + r) * HIDDEN + k0 + c];
      As[r][c] = v.x; As[r][c + 1] = v.y; As[r][c + 2] = v.z; As[r][c + 3] = v.w;
    }
    {
      int kr = t >> 4, c = (t & 15) * 4;
      float4 v = *(const float4*)&W[(k0 + kr) * HIDDEN + bn + c];
      Bs[kr][c] = v.x; Bs[kr][c + 1] = v.y; Bs[kr][c + 2] = v.z; Bs[kr][c + 3] = v.w;
    }
    __syncthreads();
#pragma unroll
    for (int k = 0; k < 16; k++) {
      float a[4], b[4];
#pragma unroll
      for (int i = 0; i < 4; i++) a[i] = As[ty * 4 + i][k];
#pragma unroll
      for (int j = 0; j < 4; j++) b[j] = Bs[k][tx * 4 + j];
#pragma unroll
      for (int i = 0; i < 4; i++)
#pragma unroll
        for (int j = 0; j < 4; j++) acc[i][j] += a[i] * b[j];
    }
    __syncthreads();
  }
#pragma unroll
  for (int i = 0; i < 4; i++) {
    int m = bm + ty * 4 + i;
#pragma unroll
    for (int j = 0; j < 4; j++) {
      int n = bn + tx * 4 + j;
      float x = acc[i][j] + bias[n];
      float g = x * 0.5f * (1.0f + erff(x * 0.70710678118654752f));
      H[m * HIDDEN + n] = g;
    }
  }
}

// ---------------- block reduction helper (256 threads) ----------------
__device__ inline float block_sum256(float v, float* red) {
  int t = threadIdx.x;
#pragma unroll
  for (int o = 32; o > 0; o >>= 1) v += __shfl_down(v, o);
  __syncthreads();  // protect previous red use
  if ((t & 63) == 0) red[t >> 6] = v;
  __syncthreads();
  return red[0] + red[1] + red[2] + red[3];
}

// ---------------- Stage 2+3: LN -> ent matvec -> sigmoid -> quantum sim -> probs(f16) ----------------
__global__ __launch_bounds__(256) void row_quantum(
    const float* __restrict__ H, const float* __restrict__ ln_w,
    const float* __restrict__ ln_b, const float* __restrict__ ent_w,
    const float* __restrict__ ent_b, _Float16* __restrict__ probsA) {
  __shared__ float hn[HIDDEN];
  __shared__ float red[4];
  __shared__ float sr[QDIM];
  __shared__ float si[QDIM];
  __shared__ float ang[20];
  int t = threadIdx.x;
  int row = blockIdx.x;
  const float* hr = H + row * HIDDEN;

  float sum = 0.f;
  for (int i = t; i < HIDDEN; i += 256) {
    float v = hr[i];
    hn[i] = v;
    sum += v;
  }
  float u = block_sum256(sum, red) * (1.0f / HIDDEN);
  float vs = 0.f;
  for (int i = t; i < HIDDEN; i += 256) {
    float d = hn[i] - u;
    vs += d * d;
  }
  float var = block_sum256(vs, red) * (1.0f / HIDDEN);
  float inv = rsqrtf(var + 1e-12f);
  for (int i = t; i < HIDDEN; i += 256)
    hn[i] = ln_w[i] * ((hn[i] - u) * inv) + ln_b[i];
  __syncthreads();

  // ent matvec: 20 outputs, threads 0..19 each a full dot (hn broadcast from LDS)
  if (t < 20) {
    float acc = ent_b[t];
#pragma unroll 4
    for (int i = 0; i < HIDDEN; i++) acc += hn[i] * ent_w[i * 20 + t];
    float s = 1.0f / (1.0f + expf(-acc));
    ang[t] = 6.283185307179586f * s;
  }
  __syncthreads();

  // init |0...0>
  for (int i = t; i < QDIM; i += 256) {
    sr[i] = (i == 0) ? 1.0f : 0.0f;
    si[i] = 0.0f;
  }
  __syncthreads();

  for (int l = 0; l < 2; l++) {
    for (int q = 0; q < 10; q++) {
      float th = ang[l * 10 + q] * 0.5f;
      float c, s;
      __sincosf(th, &s, &c);
      // use accurate versions:
      s = sinf(th); c = cosf(th);
      int bp = 9 - q;
      int mask = 1 << bp;
#pragma unroll
      for (int p = 0; p < 2; p++) {
        int pi = t + p * 256;  // 0..511
        int i0 = ((pi >> bp) << (bp + 1)) | (pi & (mask - 1));
        int i1 = i0 | mask;
        float a0r = sr[i0], a0i = si[i0], a1r = sr[i1], a1i = si[i1];
        sr[i0] = c * a0r + s * a1i;
        si[i0] = c * a0i - s * a1r;
        sr[i1] = c * a1r + s * a0i;
        si[i1] = c * a1i - s * a0r;
      }
      __syncthreads();
    }
    // CNOT ring: composed permutation, new[i] = old[P0(P1(...P9(i)))]
    float tr[4], ti[4];
#pragma unroll
    for (int p = 0; p < 4; p++) {
      int i = t + p * 256;
      int j = i;
#pragma unroll
      for (int q = 9; q >= 0; q--) {
        int cb = 9 - q;              // control bit position
        int tb = 9 - ((q + 1) % 10); // target bit position
        j ^= ((j >> cb) & 1) << tb;
      }
      tr[p] = sr[j];
      ti[p] = si[j];
    }
    __syncthreads();
#pragma unroll
    for (int p = 0; p < 4; p++) {
      int i = t + p * 256;
      sr[i] = tr[p];
      si[i] = ti[p];
    }
    __syncthreads();
  }

  for (int i = t; i < QDIM; i += 256) {
    float pv = sr[i] * sr[i] + si[i] * si[i];
    probsA[row * QDIM + i] = (_Float16)pv;
  }
}

// ---------------- Stage 4: out = probs @ proj_w + b, f16 MFMA 128x128 tile ----------------
__global__ __launch_bounds__(256) void gemm2_mfma(
    const _Float16* __restrict__ A,   // [4096][1024] f16
    const _Float16* __restrict__ BT,  // [NPAD][1024] f16 (B transposed)
    const float* __restrict__ bias,   // [VOCAB]
    float* __restrict__ C) {
  __shared__ _Float16 As[128][40];
  __shared__ _Float16 Bs[128][40];
  int t = threadIdx.x;
  int lane = t & 63, wave = t >> 6;
  int quad = lane >> 4, ln = lane & 15;
  int wm = (wave >> 1) * 64, wn = (wave & 1) * 64;
  int bm = blockIdx.y * 128;
  int bn = blockIdx.x * 128;

  floatx4 acc[4][4];
#pragma unroll
  for (int i = 0; i < 4; i++)
#pragma unroll
    for (int j = 0; j < 4; j++) acc[i][j] = (floatx4){0.f, 0.f, 0.f, 0.f};

  for (int k0 = 0; k0 < QDIM; k0 += 32) {
    __syncthreads();
#pragma unroll
    for (int cch = 0; cch < 2; cch++) {
      int idx = t + cch * 256;            // 0..511 chunks of 16B
      int r = idx >> 2, col = (idx & 3) * 8;
      *(half8*)&As[r][col] = *(const half8*)&A[(bm + r) * QDIM + k0 + col];
      *(half8*)&Bs[r][col] = *(const half8*)&BT[(bn + r) * QDIM + k0 + col];
    }
    __syncthreads();
    half8 a[4], b[4];
#pragma unroll
    for (int i = 0; i < 4; i++) a[i] = *(const half8*)&As[wm + i * 16 + ln][quad * 8];
#pragma unroll
    for (int j = 0; j < 4; j++) b[j] = *(const half8*)&Bs[wn + j * 16 + ln][quad * 8];
#pragma unroll
    for (int i = 0; i < 4; i++)
#pragma unroll
      for (int j = 0; j < 4; j++)
        acc[i][j] = __builtin_amdgcn_mfma_f32_16x16x32_f16(a[i], b[j], acc[i][j], 0, 0, 0);
  }

#pragma unroll
  for (int j = 0; j < 4; j++) {
    int n = bn + wn + j * 16 + ln;
    if (n >= VOCAB) continue;
    float bv = bias[n];
#pragma unroll
    for (int i = 0; i < 4; i++) {
#pragma unroll
      for (int r = 0; r < 4; r++) {
        int m = bm + wm + i * 16 + quad * 4 + r;
        C[(size_t)m * VOCAB + n] = acc[i][j][r] + bv;
      }
    }
  }
}

extern "C" void kernel_launch(void* const* d_in, const int* in_sizes, int n_in,
                              void* d_out, int out_size, void* d_ws, size_t ws_size,
                              hipStream_t stream) {
  const float* hs      = (const float*)d_in[0];
  const float* dense_w = (const float*)d_in[1];
  const float* dense_b = (const float*)d_in[2];
  const float* ln_w    = (const float*)d_in[3];
  const float* ln_b    = (const float*)d_in[4];
  const float* ent_w   = (const float*)d_in[5];
  const float* ent_b   = (const float*)d_in[6];
  const float* proj_w  = (const float*)d_in[7];
  const float* proj_b  = (const float*)d_in[8];
  float* out = (float*)d_out;

  char* ws = (char*)d_ws;
  float*     h      = (float*)ws;                       // 4096*768*4  = 12582912 B
  _Float16*  probsA = (_Float16*)(ws + 12582912);       // 4096*1024*2 =  8388608 B
  _Float16*  BT     = (_Float16*)(ws + 20971520);       // NPAD*1024*2 = 62652416 B

  hipLaunchKernelGGL(convert_transpose, dim3(NPAD / 32, QDIM / 32), dim3(32, 32), 0, stream,
                     proj_w, BT);
  hipLaunchKernelGGL(gemm1_gelu, dim3(HIDDEN / 64, NROWS / 64), dim3(256), 0, stream,
                     hs, dense_w, dense_b, h);
  hipLaunchKernelGGL(row_quantum, dim3(NROWS), dim3(256), 0, stream,
                     h, ln_w, ln_b, ent_w, ent_b, probsA);
  hipLaunchKernelGGL(gemm2_mfma, dim3(NPAD / 128, NROWS / 128), dim3(256), 0, stream,
                     probsA, BT, proj_b, out);
}